// Round 1
// baseline (300.015 us; speedup 1.0000x reference)
//
#include <hip/hip_runtime.h>
#include <hip/hip_bf16.h>

#define NUM_CLASSES 100000
#define DIM 256
#define BATCH 256
#define NUM_TRUE 1024
#define NUM_SAMPLED 16384
// ln(NUM_CLASSES + 1)
#define LOG_RANGE 11.51293546492023f
#define INV_LOG_RANGE (1.0f / LOG_RANGE)

typedef __bf16 bf16x8 __attribute__((ext_vector_type(8)));
typedef float  f32x4  __attribute__((ext_vector_type(4)));

// RNE float -> bf16 bits (inputs are finite; no NaN handling needed)
static __device__ __forceinline__ unsigned short f2bf(float f) {
    unsigned int u = __float_as_uint(f);
    unsigned int lsb = (u >> 16) & 1u;
    u += 0x7fffu + lsb;
    return (unsigned short)(u >> 16);
}

// -log(expected_count(id)), exact fp32 per reference formula
static __device__ __forceinline__ float neg_log_ec(int id) {
    float idf = (float)id;
    float p = logf((idf + 2.0f) / (idf + 1.0f)) * INV_LOG_RANGE;
    float ec = -expm1f((float)NUM_SAMPLED * log1pf(-p));
    return -logf(ec);
}

// stable sigmoid cross-entropy with target t: max(l,0) - l*t + log1p(exp(-|l|))
static __device__ __forceinline__ float sig_xent(float l, float t) {
    return fmaxf(l, 0.0f) - l * t + log1pf(expf(-fabsf(l)));
}

// ---------------- inputs fp32 -> bf16 (into workspace) ----------------
__global__ __launch_bounds__(256) void conv_inputs(const float* __restrict__ in,
                                                   unsigned short* __restrict__ out) {
    int idx = blockIdx.x * 256 + threadIdx.x;   // 16384 threads, 4 floats each
    float4 v = ((const float4*)in)[idx];
    ushort4 p;
    p.x = f2bf(v.x); p.y = f2bf(v.y); p.z = f2bf(v.z); p.w = f2bf(v.w);
    ((ushort4*)out)[idx] = p;
}

// ---------------- true part: wave-per-label-row dot ----------------
// grid (16 chunks, 256 batches), block 256 (4 waves); each wave does 16 labels
__global__ __launch_bounds__(256) void true_kernel(const float* __restrict__ inputs,
                                                   const float* __restrict__ w,
                                                   const float* __restrict__ bias,
                                                   const int* __restrict__ labels,
                                                   float* __restrict__ out) {
    __shared__ __align__(16) float ins[DIM];
    const int tid = threadIdx.x;
    const int b = blockIdx.y;
    ins[tid] = inputs[b * DIM + tid];
    __syncthreads();

    const int lane = tid & 63;
    const int wv   = tid >> 6;
    const float4 iv = *(const float4*)(&ins[lane * 4]);
    const int* lab = labels + b * NUM_TRUE + blockIdx.x * 64 + wv * 16;

    float acc = 0.0f;
    int l = lab[0];
    float4 wr = *(const float4*)(w + (size_t)l * DIM + lane * 4);
    float bl = bias[l];

    #pragma unroll 4
    for (int i = 0; i < 16; ++i) {
        int ln = 0; float4 wn = {0,0,0,0}; float bn = 0.0f;
        if (i < 15) {  // prefetch next row while reducing current
            ln = lab[i + 1];
            wn = *(const float4*)(w + (size_t)ln * DIM + lane * 4);
            bn = bias[ln];
        }
        float p = wr.x * iv.x + wr.y * iv.y + wr.z * iv.z + wr.w * iv.w;
        p += __shfl_xor(p, 32); p += __shfl_xor(p, 16); p += __shfl_xor(p, 8);
        p += __shfl_xor(p, 4);  p += __shfl_xor(p, 2);  p += __shfl_xor(p, 1);
        float logit = p + bl + neg_log_ec(l);
        acc += sig_xent(logit, 1.0f / (float)NUM_TRUE);
        l = ln; wr = wn; bl = bn;
    }
    if (lane == 0) atomicAdd(&out[b], acc);
}

// ---------------- sampled part: bf16 MFMA GEMM + xent epilogue ----------------
// grid 256 blocks (64 sampled rows each), block 256 (4 waves).
// Block tile per b-chunk: 64 s x 64 b, wave tile 32 s x 32 b, K = 256.
#define LWS 264   // 256 + 8 bf16 pad: keeps 16B alignment, rows stride 528B
__global__ __launch_bounds__(256) void sampled_kernel(const float* __restrict__ w,
                                                      const float* __restrict__ bias,
                                                      const int* __restrict__ sampled,
                                                      const unsigned short* __restrict__ inbf,
                                                      float* __restrict__ out) {
    __shared__ unsigned short lw[64][LWS];   // w_sampled tile, bf16
    __shared__ unsigned short li[64][LWS];   // inputs b-chunk tile, bf16
    __shared__ float cs[64];                 // bias[id] - log(ec(id))
    __shared__ float bacc[BATCH];            // per-block partial sums over s

    const int tid = threadIdx.x;
    const int s0 = blockIdx.x * 64;
    bacc[tid] = 0.0f;

    // stage w tile: row = tid&63 so consecutive lanes hit distinct LDS bank spans
    const int row = tid & 63;
    const int seg = tid >> 6;               // 4 segments of 64 elements
    {
        const int id = sampled[s0 + row];
        const float4* src = (const float4*)(w + (size_t)id * DIM + seg * 64);
        #pragma unroll
        for (int j = 0; j < 16; ++j) {
            float4 v = src[j];
            ushort4 pk;
            pk.x = f2bf(v.x); pk.y = f2bf(v.y); pk.z = f2bf(v.z); pk.w = f2bf(v.w);
            *(ushort4*)(&lw[row][seg * 64 + j * 4]) = pk;
        }
        if (seg == 0) cs[row] = bias[id] + neg_log_ec(id);
    }

    const int lane = tid & 63;
    const int wv   = tid >> 6;
    const int m    = lane & 15;
    const int quad = lane >> 4;
    const int wy   = wv & 1;    // s half
    const int wx   = wv >> 1;   // b half

    for (int chunk = 0; chunk < 4; ++chunk) {
        __syncthreads();
        // stage inputs chunk (64 b x 256 k, bf16 from ws)
        {
            const int4* isrc = (const int4*)(inbf + ((chunk * 64 + row) * DIM + seg * 64));
            int4* idst = (int4*)(&li[row][seg * 64]);
            #pragma unroll
            for (int j = 0; j < 8; ++j) idst[j] = isrc[j];
        }
        __syncthreads();

        f32x4 acc00 = {0,0,0,0}, acc01 = {0,0,0,0}, acc10 = {0,0,0,0}, acc11 = {0,0,0,0};
        const unsigned short* pa0 = &lw[wy * 32 + m][quad * 8];
        const unsigned short* pa1 = &lw[wy * 32 + 16 + m][quad * 8];
        const unsigned short* pb0 = &li[wx * 32 + m][quad * 8];
        const unsigned short* pb1 = &li[wx * 32 + 16 + m][quad * 8];
        #pragma unroll
        for (int kk = 0; kk < 8; ++kk) {
            bf16x8 a0 = *(const bf16x8*)(pa0 + kk * 32);
            bf16x8 a1 = *(const bf16x8*)(pa1 + kk * 32);
            bf16x8 b0 = *(const bf16x8*)(pb0 + kk * 32);
            bf16x8 b1 = *(const bf16x8*)(pb1 + kk * 32);
            acc00 = __builtin_amdgcn_mfma_f32_16x16x32_bf16(a0, b0, acc00, 0, 0, 0);
            acc01 = __builtin_amdgcn_mfma_f32_16x16x32_bf16(a0, b1, acc01, 0, 0, 0);
            acc10 = __builtin_amdgcn_mfma_f32_16x16x32_bf16(a1, b0, acc10, 0, 0, 0);
            acc11 = __builtin_amdgcn_mfma_f32_16x16x32_bf16(a1, b1, acc11, 0, 0, 0);
        }

        // epilogue: logits -> xent(target 0) -> sum over the wave's 32 s rows
        // C/D layout: col(b) = lane&15, row(s) = quad*4 + reg
        float ps0 = 0.0f, ps1 = 0.0f;
        #pragma unroll
        for (int r = 0; r < 4; ++r) {
            {
                float c = cs[wy * 32 + quad * 4 + r];
                float l0 = acc00[r] + c;
                ps0 += fmaxf(l0, 0.0f) + log1pf(expf(-fabsf(l0)));
                float l1 = acc01[r] + c;
                ps1 += fmaxf(l1, 0.0f) + log1pf(expf(-fabsf(l1)));
            }
            {
                float c = cs[wy * 32 + 16 + quad * 4 + r];
                float l0 = acc10[r] + c;
                ps0 += fmaxf(l0, 0.0f) + log1pf(expf(-fabsf(l0)));
                float l1 = acc11[r] + c;
                ps1 += fmaxf(l1, 0.0f) + log1pf(expf(-fabsf(l1)));
            }
        }
        // reduce over quads (s dimension spread across lane>>4)
        ps0 += __shfl_xor(ps0, 16); ps0 += __shfl_xor(ps0, 32);
        ps1 += __shfl_xor(ps1, 16); ps1 += __shfl_xor(ps1, 32);
        if (quad == 0) {
            atomicAdd(&bacc[chunk * 64 + wx * 32 + m], ps0);
            atomicAdd(&bacc[chunk * 64 + wx * 32 + 16 + m], ps1);
        }
    }
    __syncthreads();
    atomicAdd(&out[tid], bacc[tid]);
}

extern "C" void kernel_launch(void* const* d_in, const int* in_sizes, int n_in,
                              void* d_out, int out_size, void* d_ws, size_t ws_size,
                              hipStream_t stream) {
    const float* inputs  = (const float*)d_in[0];   // [256,256]
    const float* w       = (const float*)d_in[1];   // [100000,256]
    const float* bias    = (const float*)d_in[2];   // [100000]
    const int*   labels  = (const int*)d_in[3];     // [256,1024]
    const int*   sampled = (const int*)d_in[4];     // [16384]
    float* out = (float*)d_out;                     // [256]
    unsigned short* inbf = (unsigned short*)d_ws;   // 256*256 bf16 = 128 KB

    hipMemsetAsync(out, 0, BATCH * sizeof(float), stream);
    conv_inputs<<<64, 256, 0, stream>>>(inputs, inbf);
    true_kernel<<<dim3(16, 256), 256, 0, stream>>>(inputs, w, bias, labels, out);
    sampled_kernel<<<NUM_SAMPLED / 64, 256, 0, stream>>>(w, bias, sampled, inbf, out);
}

// Round 2
// 208.993 us; speedup vs baseline: 1.4355x; 1.4355x over previous
//
#include <hip/hip_runtime.h>
#include <hip/hip_bf16.h>

#define NUM_CLASSES 100000
#define DIM 256
#define BATCH 256
#define NUM_TRUE 1024
#define NUM_SAMPLED 16384
// ln(NUM_CLASSES + 1)
#define LOG_RANGE 11.51293546492023f
#define INV_LOG_RANGE (1.0f / LOG_RANGE)

typedef __bf16 bf16x8 __attribute__((ext_vector_type(8)));
typedef float  f32x4  __attribute__((ext_vector_type(4)));

// RNE float -> bf16 bits
static __device__ __forceinline__ unsigned short f2bf(float f) {
    unsigned int u = __float_as_uint(f);
    unsigned int lsb = (u >> 16) & 1u;
    u += 0x7fffu + lsb;
    return (unsigned short)(u >> 16);
}

// -log(expected_count(id)), precise libm (matches numpy fp32 closely)
static __device__ __forceinline__ float neg_log_ec(int id) {
    float idf = (float)id;
    float p = logf((idf + 2.0f) / (idf + 1.0f)) * INV_LOG_RANGE;
    float ec = -expm1f((float)NUM_SAMPLED * log1pf(-p));
    return -logf(ec);
}

static __device__ __forceinline__ void fma4(float4& acc, float4 a, float4 b) {
    acc.x = fmaf(a.x, b.x, acc.x);
    acc.y = fmaf(a.y, b.y, acc.y);
    acc.z = fmaf(a.z, b.z, acc.z);
    acc.w = fmaf(a.w, b.w, acc.w);
}

// ---------------- inputs fp32 -> bf16 (into workspace) ----------------
__global__ __launch_bounds__(256) void conv_inputs(const float* __restrict__ in,
                                                   unsigned short* __restrict__ out) {
    int idx = blockIdx.x * 256 + threadIdx.x;
    float4 v = ((const float4*)in)[idx];
    ushort4 p;
    p.x = f2bf(v.x); p.y = f2bf(v.y); p.z = f2bf(v.z); p.w = f2bf(v.w);
    ((ushort4*)out)[idx] = p;
}

// ---------------- true part: THREAD-per-label ----------------
// grid (4, 256): block = 256 labels of batch b. Each thread streams its own
// w row (64 float4 loads); input row is a broadcast LDS read (uniform addr).
// Epilogue transcendentals computed exactly once per label (not 64x/wave).
__global__ __launch_bounds__(256) void true_kernel(const float* __restrict__ inputs,
                                                   const float* __restrict__ w,
                                                   const float* __restrict__ bias,
                                                   const int* __restrict__ labels,
                                                   float* __restrict__ out) {
    __shared__ __align__(16) float ins[DIM];
    __shared__ float wsum[4];
    const int tid = threadIdx.x;
    const int b = blockIdx.y;
    ins[tid] = inputs[b * DIM + tid];
    __syncthreads();

    const int t = blockIdx.x * 256 + tid;
    const int l = labels[b * NUM_TRUE + t];
    const float bl = bias[l];                       // issue early
    const float4* __restrict__ wr = (const float4*)(w + (size_t)l * DIM);
    const float4* __restrict__ ir = (const float4*)ins;

    float4 a0 = {0,0,0,0}, a1 = {0,0,0,0}, a2 = {0,0,0,0}, a3 = {0,0,0,0};
    // 64 float4 loads; unroll 4 -> 16 loads in flight per thread
    #pragma unroll 4
    for (int k = 0; k < 16; ++k) {
        float4 w0 = wr[k * 4 + 0];
        float4 w1 = wr[k * 4 + 1];
        float4 w2 = wr[k * 4 + 2];
        float4 w3 = wr[k * 4 + 3];
        fma4(a0, w0, ir[k * 4 + 0]);
        fma4(a1, w1, ir[k * 4 + 1]);
        fma4(a2, w2, ir[k * 4 + 2]);
        fma4(a3, w3, ir[k * 4 + 3]);
    }
    float dot = (a0.x + a0.y + a0.z + a0.w) + (a1.x + a1.y + a1.z + a1.w)
              + (a2.x + a2.y + a2.z + a2.w) + (a3.x + a3.y + a3.z + a3.w);

    float logit = dot + bl + neg_log_ec(l);
    const float tgt = 1.0f / (float)NUM_TRUE;
    float v = fmaxf(logit, 0.0f) - logit * tgt + log1pf(expf(-fabsf(logit)));

    // block reduce (all threads share b)
    v += __shfl_xor(v, 1);  v += __shfl_xor(v, 2);  v += __shfl_xor(v, 4);
    v += __shfl_xor(v, 8);  v += __shfl_xor(v, 16); v += __shfl_xor(v, 32);
    if ((tid & 63) == 0) wsum[tid >> 6] = v;
    __syncthreads();
    if (tid == 0) atomicAdd(&out[b], wsum[0] + wsum[1] + wsum[2] + wsum[3]);
}

// ---------------- sampled part: bf16 MFMA GEMM + xent epilogue ----------------
// grid 256 blocks (64 sampled rows each), block 256 (4 waves).
// Partial sums go to ws (no global atomics); reduce_kernel finishes.
#define LWS 264
__global__ __launch_bounds__(256) void sampled_kernel(const float* __restrict__ w,
                                                      const float* __restrict__ bias,
                                                      const int* __restrict__ sampled,
                                                      const unsigned short* __restrict__ inbf,
                                                      float* __restrict__ partial) {
    __shared__ unsigned short lw[64][LWS];
    __shared__ unsigned short li[64][LWS];
    __shared__ float cs[64];
    __shared__ float bacc[BATCH];

    const int tid = threadIdx.x;
    const int s0 = blockIdx.x * 64;
    bacc[tid] = 0.0f;

    const int row = tid & 63;
    const int seg = tid >> 6;
    {
        const int id = sampled[s0 + row];
        const float4* src = (const float4*)(w + (size_t)id * DIM + seg * 64);
        #pragma unroll
        for (int j = 0; j < 16; ++j) {
            float4 v = src[j];
            ushort4 pk;
            pk.x = f2bf(v.x); pk.y = f2bf(v.y); pk.z = f2bf(v.z); pk.w = f2bf(v.w);
            *(ushort4*)(&lw[row][seg * 64 + j * 4]) = pk;
        }
        if (seg == 0) cs[row] = bias[id] + neg_log_ec(id);
    }

    const int lane = tid & 63;
    const int wv   = tid >> 6;
    const int m    = lane & 15;
    const int quad = lane >> 4;
    const int wy   = wv & 1;
    const int wx   = wv >> 1;

    for (int chunk = 0; chunk < 4; ++chunk) {
        __syncthreads();
        {
            const int4* isrc = (const int4*)(inbf + ((chunk * 64 + row) * DIM + seg * 64));
            int4* idst = (int4*)(&li[row][seg * 64]);
            #pragma unroll
            for (int j = 0; j < 8; ++j) idst[j] = isrc[j];
        }
        __syncthreads();

        f32x4 acc00 = {0,0,0,0}, acc01 = {0,0,0,0}, acc10 = {0,0,0,0}, acc11 = {0,0,0,0};
        const unsigned short* pa0 = &lw[wy * 32 + m][quad * 8];
        const unsigned short* pa1 = &lw[wy * 32 + 16 + m][quad * 8];
        const unsigned short* pb0 = &li[wx * 32 + m][quad * 8];
        const unsigned short* pb1 = &li[wx * 32 + 16 + m][quad * 8];
        #pragma unroll
        for (int kk = 0; kk < 8; ++kk) {
            bf16x8 a0 = *(const bf16x8*)(pa0 + kk * 32);
            bf16x8 a1 = *(const bf16x8*)(pa1 + kk * 32);
            bf16x8 b0 = *(const bf16x8*)(pb0 + kk * 32);
            bf16x8 b1 = *(const bf16x8*)(pb1 + kk * 32);
            acc00 = __builtin_amdgcn_mfma_f32_16x16x32_bf16(a0, b0, acc00, 0, 0, 0);
            acc01 = __builtin_amdgcn_mfma_f32_16x16x32_bf16(a0, b1, acc01, 0, 0, 0);
            acc10 = __builtin_amdgcn_mfma_f32_16x16x32_bf16(a1, b0, acc10, 0, 0, 0);
            acc11 = __builtin_amdgcn_mfma_f32_16x16x32_bf16(a1, b1, acc11, 0, 0, 0);
        }

        // xent(target 0) = max(l,0) + log(1+exp(-|l|)); fast intrinsics (4.2M evals)
        float ps0 = 0.0f, ps1 = 0.0f;
        #pragma unroll
        for (int r = 0; r < 4; ++r) {
            {
                float c = cs[wy * 32 + quad * 4 + r];
                float l0 = acc00[r] + c;
                ps0 += fmaxf(l0, 0.0f) + __logf(1.0f + __expf(-fabsf(l0)));
                float l1 = acc01[r] + c;
                ps1 += fmaxf(l1, 0.0f) + __logf(1.0f + __expf(-fabsf(l1)));
            }
            {
                float c = cs[wy * 32 + 16 + quad * 4 + r];
                float l0 = acc10[r] + c;
                ps0 += fmaxf(l0, 0.0f) + __logf(1.0f + __expf(-fabsf(l0)));
                float l1 = acc11[r] + c;
                ps1 += fmaxf(l1, 0.0f) + __logf(1.0f + __expf(-fabsf(l1)));
            }
        }
        ps0 += __shfl_xor(ps0, 16); ps0 += __shfl_xor(ps0, 32);
        ps1 += __shfl_xor(ps1, 16); ps1 += __shfl_xor(ps1, 32);
        if (quad == 0) {
            atomicAdd(&bacc[chunk * 64 + wx * 32 + m], ps0);
            atomicAdd(&bacc[chunk * 64 + wx * 32 + 16 + m], ps1);
        }
    }
    __syncthreads();
    partial[blockIdx.x * BATCH + tid] = bacc[tid];   // coalesced, NO global atomics
}

// ---------------- final reduce: out[b] += sum_p partial[p][b] ----------------
__global__ __launch_bounds__(256) void reduce_kernel(const float* __restrict__ partial,
                                                     float* __restrict__ out) {
    __shared__ float wsum[4];
    const int b = blockIdx.x;
    const int tid = threadIdx.x;
    float v = partial[tid * BATCH + b];
    v += __shfl_xor(v, 1);  v += __shfl_xor(v, 2);  v += __shfl_xor(v, 4);
    v += __shfl_xor(v, 8);  v += __shfl_xor(v, 16); v += __shfl_xor(v, 32);
    if ((tid & 63) == 0) wsum[tid >> 6] = v;
    __syncthreads();
    if (tid == 0) out[b] += wsum[0] + wsum[1] + wsum[2] + wsum[3];  // after true_kernel (stream-ordered)
}

extern "C" void kernel_launch(void* const* d_in, const int* in_sizes, int n_in,
                              void* d_out, int out_size, void* d_ws, size_t ws_size,
                              hipStream_t stream) {
    const float* inputs  = (const float*)d_in[0];   // [256,256]
    const float* w       = (const float*)d_in[1];   // [100000,256]
    const float* bias    = (const float*)d_in[2];   // [100000]
    const int*   labels  = (const int*)d_in[3];     // [256,1024]
    const int*   sampled = (const int*)d_in[4];     // [16384]
    float* out = (float*)d_out;                     // [256]

    unsigned short* inbf = (unsigned short*)d_ws;                    // 128 KB
    float* partial = (float*)((char*)d_ws + BATCH * DIM * 2);        // 256 KB

    hipMemsetAsync(out, 0, BATCH * sizeof(float), stream);
    conv_inputs<<<64, 256, 0, stream>>>(inputs, inbf);
    true_kernel<<<dim3(4, 256), 256, 0, stream>>>(inputs, w, bias, labels, out);
    sampled_kernel<<<NUM_SAMPLED / 64, 256, 0, stream>>>(w, bias, sampled, inbf, partial);
    reduce_kernel<<<BATCH, 256, 0, stream>>>(partial, out);
}

// Round 3
// 195.056 us; speedup vs baseline: 1.5381x; 1.0715x over previous
//
#include <hip/hip_runtime.h>
#include <hip/hip_bf16.h>

#define NUM_CLASSES 100000
#define DIM 256
#define BATCH 256
#define NUM_TRUE 1024
#define NUM_SAMPLED 16384
// ln(NUM_CLASSES + 1)
#define LOG_RANGE 11.51293546492023f
#define INV_LOG_RANGE (1.0f / LOG_RANGE)

typedef __bf16 bf16x8 __attribute__((ext_vector_type(8)));
typedef float  f32x4  __attribute__((ext_vector_type(4)));

// RNE float -> bf16 bits
static __device__ __forceinline__ unsigned short f2bf(float f) {
    unsigned int u = __float_as_uint(f);
    unsigned int lsb = (u >> 16) & 1u;
    u += 0x7fffu + lsb;
    return (unsigned short)(u >> 16);
}

// -log(expected_count(id)), precise libm (done once per class, in comb_kernel)
static __device__ __forceinline__ float neg_log_ec(int id) {
    float idf = (float)id;
    float p = logf((idf + 2.0f) / (idf + 1.0f)) * INV_LOG_RANGE;
    float ec = -expm1f((float)NUM_SAMPLED * log1pf(-p));
    return -logf(ec);
}

static __device__ __forceinline__ float dot4(float4 a, float4 b) {
    return fmaf(a.x, b.x, fmaf(a.y, b.y, fmaf(a.z, b.z, a.w * b.w)));
}

// ---------------- per-class constant: comb[c] = bias[c] - log(ec(c)) ----------------
__global__ __launch_bounds__(256) void comb_kernel(const float* __restrict__ bias,
                                                   float* __restrict__ comb) {
    int c = blockIdx.x * 256 + threadIdx.x;
    if (c < NUM_CLASSES) comb[c] = bias[c] + neg_log_ec(c);
}

// ---------------- true part: 16 lanes per label (coalesced 256B segments) --------
// grid (8, 256): block = 128 labels of batch b; wave = 32 labels, 4 per iteration.
// Each wave-load covers 4 rows x 256B contiguous -> 16 cache lines (vs 64 for
// thread-per-label), cutting TA address-processing 4x.
__global__ __launch_bounds__(256) void true_kernel(const float* __restrict__ inputs,
                                                   const float* __restrict__ w,
                                                   const float* __restrict__ comb,
                                                   const int* __restrict__ labels,
                                                   float* __restrict__ out) {
    __shared__ __align__(16) float ins[DIM];
    __shared__ float wsum[4];
    const int tid = threadIdx.x;
    const int b = blockIdx.y;
    ins[tid] = inputs[b * DIM + tid];
    __syncthreads();

    const int lane = tid & 63;
    const int wv   = tid >> 6;
    const int sub  = lane >> 4;    // which of 4 labels this iteration
    const int part = lane & 15;    // position within the row
    const float4* ir = (const float4*)ins;
    const float4 in0 = ir[part], in1 = ir[16 + part], in2 = ir[32 + part], in3 = ir[48 + part];

    const int* lab = labels + b * NUM_TRUE + blockIdx.x * 128 + wv * 32;

    float acc = 0.0f;
    float4 w0, w1, w2, w3;
    float cl;
    {
        int l = lab[sub];
        const float4* wr = (const float4*)(w + (size_t)l * DIM);
        w0 = wr[part]; w1 = wr[16 + part]; w2 = wr[32 + part]; w3 = wr[48 + part];
        cl = comb[l];
    }

    #pragma unroll
    for (int i = 0; i < 8; ++i) {
        float4 n0 = {0,0,0,0}, n1 = {0,0,0,0}, n2 = {0,0,0,0}, n3 = {0,0,0,0};
        float cn = 0.0f;
        if (i < 7) {  // prefetch next 4 rows while reducing current
            int ln = lab[(i + 1) * 4 + sub];
            const float4* wr = (const float4*)(w + (size_t)ln * DIM);
            n0 = wr[part]; n1 = wr[16 + part]; n2 = wr[32 + part]; n3 = wr[48 + part];
            cn = comb[ln];
        }
        float d = dot4(w0, in0) + dot4(w1, in1) + dot4(w2, in2) + dot4(w3, in3);
        d += __shfl_xor(d, 1); d += __shfl_xor(d, 2);
        d += __shfl_xor(d, 4); d += __shfl_xor(d, 8);
        // all 16 lanes of the sub-group hold the full dot: epilogue is group-uniform
        float logit = d + cl;
        float v = fmaxf(logit, 0.0f) - logit * (1.0f / (float)NUM_TRUE)
                + log1pf(expf(-fabsf(logit)));
        acc += (part == 0) ? v : 0.0f;
        w0 = n0; w1 = n1; w2 = n2; w3 = n3; cl = cn;
    }
    // lanes 0,16,32,48 hold partials
    acc += __shfl_xor(acc, 16); acc += __shfl_xor(acc, 32);
    if (lane == 0) wsum[wv] = acc;
    __syncthreads();
    if (tid == 0) atomicAdd(&out[b], wsum[0] + wsum[1] + wsum[2] + wsum[3]);
}

// ---------------- sampled part: bf16 MFMA GEMM + xent epilogue ----------------
// grid (256, 2): block = 64 sampled rows x 128 batch (2 chunks of 64).
// LDS 68 KB -> 2 blocks/CU resident. Inputs staged bf16 directly from fp32.
#define LWS 264
__global__ __launch_bounds__(256) void sampled_kernel(const float* __restrict__ w,
                                                      const float* __restrict__ comb,
                                                      const int* __restrict__ sampled,
                                                      const float* __restrict__ inputs,
                                                      float* __restrict__ partial) {
    __shared__ unsigned short lw[64][LWS];
    __shared__ unsigned short li[64][LWS];
    __shared__ float cs[64];
    __shared__ float bacc[128];

    const int tid = threadIdx.x;
    const int s0 = blockIdx.x * 64;
    const int bhalf = blockIdx.y;        // which 128-batch half
    if (tid < 128) bacc[tid] = 0.0f;

    const int row = tid & 63;
    const int seg = tid >> 6;
    {
        const int id = sampled[s0 + row];
        const float4* src = (const float4*)(w + (size_t)id * DIM + seg * 64);
        #pragma unroll
        for (int j = 0; j < 16; ++j) {
            float4 v = src[j];
            ushort4 pk;
            pk.x = f2bf(v.x); pk.y = f2bf(v.y); pk.z = f2bf(v.z); pk.w = f2bf(v.w);
            *(ushort4*)(&lw[row][seg * 64 + j * 4]) = pk;
        }
        if (seg == 0) cs[row] = comb[id];
    }

    const int lane = tid & 63;
    const int wv   = tid >> 6;
    const int m    = lane & 15;
    const int quad = lane >> 4;
    const int wy   = wv & 1;
    const int wx   = wv >> 1;

    for (int chunk = 0; chunk < 2; ++chunk) {
        __syncthreads();
        {   // stage 64 input rows (fp32 -> bf16) for this chunk
            const int bg = bhalf * 128 + chunk * 64 + row;
            const float4* isrc = (const float4*)(inputs + bg * DIM + seg * 64);
            #pragma unroll
            for (int j = 0; j < 16; ++j) {
                float4 v = isrc[j];
                ushort4 pk;
                pk.x = f2bf(v.x); pk.y = f2bf(v.y); pk.z = f2bf(v.z); pk.w = f2bf(v.w);
                *(ushort4*)(&li[row][seg * 64 + j * 4]) = pk;
            }
        }
        __syncthreads();

        f32x4 acc00 = {0,0,0,0}, acc01 = {0,0,0,0}, acc10 = {0,0,0,0}, acc11 = {0,0,0,0};
        const unsigned short* pa0 = &lw[wy * 32 + m][quad * 8];
        const unsigned short* pa1 = &lw[wy * 32 + 16 + m][quad * 8];
        const unsigned short* pb0 = &li[wx * 32 + m][quad * 8];
        const unsigned short* pb1 = &li[wx * 32 + 16 + m][quad * 8];
        #pragma unroll
        for (int kk = 0; kk < 8; ++kk) {
            bf16x8 a0 = *(const bf16x8*)(pa0 + kk * 32);
            bf16x8 a1 = *(const bf16x8*)(pa1 + kk * 32);
            bf16x8 b0 = *(const bf16x8*)(pb0 + kk * 32);
            bf16x8 b1 = *(const bf16x8*)(pb1 + kk * 32);
            acc00 = __builtin_amdgcn_mfma_f32_16x16x32_bf16(a0, b0, acc00, 0, 0, 0);
            acc01 = __builtin_amdgcn_mfma_f32_16x16x32_bf16(a0, b1, acc01, 0, 0, 0);
            acc10 = __builtin_amdgcn_mfma_f32_16x16x32_bf16(a1, b0, acc10, 0, 0, 0);
            acc11 = __builtin_amdgcn_mfma_f32_16x16x32_bf16(a1, b1, acc11, 0, 0, 0);
        }

        // xent(target 0) = max(l,0) + log(1+exp(-|l|))
        float ps0 = 0.0f, ps1 = 0.0f;
        #pragma unroll
        for (int r = 0; r < 4; ++r) {
            {
                float c = cs[wy * 32 + quad * 4 + r];
                float l0 = acc00[r] + c;
                ps0 += fmaxf(l0, 0.0f) + __logf(1.0f + __expf(-fabsf(l0)));
                float l1 = acc01[r] + c;
                ps1 += fmaxf(l1, 0.0f) + __logf(1.0f + __expf(-fabsf(l1)));
            }
            {
                float c = cs[wy * 32 + 16 + quad * 4 + r];
                float l0 = acc10[r] + c;
                ps0 += fmaxf(l0, 0.0f) + __logf(1.0f + __expf(-fabsf(l0)));
                float l1 = acc11[r] + c;
                ps1 += fmaxf(l1, 0.0f) + __logf(1.0f + __expf(-fabsf(l1)));
            }
        }
        ps0 += __shfl_xor(ps0, 16); ps0 += __shfl_xor(ps0, 32);
        ps1 += __shfl_xor(ps1, 16); ps1 += __shfl_xor(ps1, 32);
        if (quad == 0) {
            atomicAdd(&bacc[chunk * 64 + wx * 32 + m], ps0);
            atomicAdd(&bacc[chunk * 64 + wx * 32 + 16 + m], ps1);
        }
    }
    __syncthreads();
    if (tid < 128)
        partial[(bhalf * 256 + blockIdx.x) * 128 + tid] = bacc[tid];
}

// ---------------- final reduce: out[b] += sum over 256 blocks of b's half -------
__global__ __launch_bounds__(256) void reduce_kernel(const float* __restrict__ partial,
                                                     float* __restrict__ out) {
    __shared__ float wsum[4];
    const int b = blockIdx.x;
    const int tid = threadIdx.x;
    const int y = b >> 7, lb = b & 127;
    float v = partial[(y * 256 + tid) * 128 + lb];
    v += __shfl_xor(v, 1);  v += __shfl_xor(v, 2);  v += __shfl_xor(v, 4);
    v += __shfl_xor(v, 8);  v += __shfl_xor(v, 16); v += __shfl_xor(v, 32);
    if ((tid & 63) == 0) wsum[tid >> 6] = v;
    __syncthreads();
    if (tid == 0) out[b] += wsum[0] + wsum[1] + wsum[2] + wsum[3];
}

extern "C" void kernel_launch(void* const* d_in, const int* in_sizes, int n_in,
                              void* d_out, int out_size, void* d_ws, size_t ws_size,
                              hipStream_t stream) {
    const float* inputs  = (const float*)d_in[0];   // [256,256]
    const float* w       = (const float*)d_in[1];   // [100000,256]
    const float* bias    = (const float*)d_in[2];   // [100000]
    const int*   labels  = (const int*)d_in[3];     // [256,1024]
    const int*   sampled = (const int*)d_in[4];     // [16384]
    float* out = (float*)d_out;                     // [256]

    float* comb    = (float*)d_ws;                          // 400000 B
    float* partial = (float*)((char*)d_ws + 409600);        // 512*128*4 = 256 KB

    hipMemsetAsync(out, 0, BATCH * sizeof(float), stream);
    comb_kernel<<<(NUM_CLASSES + 255) / 256, 256, 0, stream>>>(bias, comb);
    true_kernel<<<dim3(8, 256), 256, 0, stream>>>(inputs, w, comb, labels, out);
    sampled_kernel<<<dim3(256, 2), 256, 0, stream>>>(w, comb, sampled, inputs, partial);
    reduce_kernel<<<BATCH, 256, 0, stream>>>(partial, out);
}

// Round 4
// 189.575 us; speedup vs baseline: 1.5826x; 1.0289x over previous
//
#include <hip/hip_runtime.h>
#include <hip/hip_bf16.h>

#define NUM_CLASSES 100000
#define DIM 256
#define BATCH 256
#define NUM_TRUE 1024
#define NUM_SAMPLED 16384
// ln(NUM_CLASSES + 1)
#define LOG_RANGE 11.51293546492023f
#define INV_LOG_RANGE (1.0f / LOG_RANGE)

typedef __bf16 bf16x8 __attribute__((ext_vector_type(8)));
typedef float  f32x4  __attribute__((ext_vector_type(4)));

// RNE float -> bf16 bits
static __device__ __forceinline__ unsigned short f2bf(float f) {
    unsigned int u = __float_as_uint(f);
    unsigned int lsb = (u >> 16) & 1u;
    u += 0x7fffu + lsb;
    return (unsigned short)(u >> 16);
}

// -log(expected_count(id)), precise libm (once per class, in comb_kernel only)
static __device__ __forceinline__ float neg_log_ec(int id) {
    float idf = (float)id;
    float p = logf((idf + 2.0f) / (idf + 1.0f)) * INV_LOG_RANGE;
    float ec = -expm1f((float)NUM_SAMPLED * log1pf(-p));
    return -logf(ec);
}

static __device__ __forceinline__ float dot4(float4 a, float4 b) {
    return fmaf(a.x, b.x, fmaf(a.y, b.y, fmaf(a.z, b.z, a.w * b.w)));
}

// ---------------- per-class constant: comb[c] = bias[c] - log(ec(c)) ----------------
__global__ __launch_bounds__(256) void comb_kernel(const float* __restrict__ bias,
                                                   float* __restrict__ comb) {
    int c = blockIdx.x * 256 + threadIdx.x;
    if (c < NUM_CLASSES) comb[c] = bias[c] + neg_log_ec(c);
}

// ---------------- true part: 16 lanes/label, depth-2 pipelined ----------------
// grid (8, 256): block = 128 labels of batch b; wave = 32 labels, 4/iter.
// Depth-2 prefetch: 8 float4 loads in flight per lane; each wave-load covers
// 4 rows x 256B contiguous (16 lines). Fast-math epilogue (comb is precise).
__global__ __launch_bounds__(256) void true_kernel(const float* __restrict__ inputs,
                                                   const float* __restrict__ w,
                                                   const float* __restrict__ comb,
                                                   const int* __restrict__ labels,
                                                   float* __restrict__ truep) {
    __shared__ __align__(16) float ins[DIM];
    __shared__ float wsum[4];
    const int tid = threadIdx.x;
    const int b = blockIdx.y;
    ins[tid] = inputs[b * DIM + tid];
    __syncthreads();

    const int lane = tid & 63;
    const int wv   = tid >> 6;
    const int sub  = lane >> 4;    // which of 4 labels this iteration
    const int part = lane & 15;    // position within the row
    const float4* ir = (const float4*)ins;
    const float4 in0 = ir[part], in1 = ir[16 + part], in2 = ir[32 + part], in3 = ir[48 + part];

    const int* lab = labels + b * NUM_TRUE + blockIdx.x * 128 + wv * 32;

    float4 buf[2][4];
    float  cb[2];
    #pragma unroll
    for (int s = 0; s < 2; ++s) {
        int l = lab[s * 4 + sub];
        const float4* wr = (const float4*)(w + (size_t)l * DIM);
        buf[s][0] = wr[part];      buf[s][1] = wr[16 + part];
        buf[s][2] = wr[32 + part]; buf[s][3] = wr[48 + part];
        cb[s] = comb[l];
    }

    float acc = 0.0f;
    #pragma unroll
    for (int i = 0; i < 8; ++i) {
        const int cur = i & 1;
        float4 w0 = buf[cur][0], w1 = buf[cur][1], w2 = buf[cur][2], w3 = buf[cur][3];
        float cl = cb[cur];
        if (i < 6) {   // refill the consumed slot two iterations ahead
            int l = lab[(i + 2) * 4 + sub];
            const float4* wr = (const float4*)(w + (size_t)l * DIM);
            buf[cur][0] = wr[part];      buf[cur][1] = wr[16 + part];
            buf[cur][2] = wr[32 + part]; buf[cur][3] = wr[48 + part];
            cb[cur] = comb[l];
        }
        float d = dot4(w0, in0) + dot4(w1, in1) + dot4(w2, in2) + dot4(w3, in3);
        d += __shfl_xor(d, 1); d += __shfl_xor(d, 2);
        d += __shfl_xor(d, 4); d += __shfl_xor(d, 8);
        float logit = d + cl;
        float v = fmaxf(logit, 0.0f) - logit * (1.0f / (float)NUM_TRUE)
                + __logf(1.0f + __expf(-fabsf(logit)));
        acc += (part == 0) ? v : 0.0f;
    }
    acc += __shfl_xor(acc, 16); acc += __shfl_xor(acc, 32);
    if (lane == 0) wsum[wv] = acc;
    __syncthreads();
    if (tid == 0) truep[b * 8 + blockIdx.x] = wsum[0] + wsum[1] + wsum[2] + wsum[3];
}

// ---------------- sampled part: bf16 MFMA GEMM + xent epilogue ----------------
// grid 256 blocks (64 sampled rows x all 256 batch in 4 chunks), block 256.
// Staging pattern: 16 lanes per row -> each wave-load = 4 rows x 256B = 16 lines.
#define LWS 264
__global__ __launch_bounds__(256) void sampled_kernel(const float* __restrict__ w,
                                                      const float* __restrict__ comb,
                                                      const int* __restrict__ sampled,
                                                      const float* __restrict__ inputs,
                                                      float* __restrict__ partial) {
    __shared__ unsigned short lw[64][LWS];
    __shared__ unsigned short li[64][LWS];
    __shared__ float cs[64];
    __shared__ float bacc[BATCH];

    const int tid = threadIdx.x;
    const int s0 = blockIdx.x * 64;
    bacc[tid] = 0.0f;

    const int inner = tid & 15;    // 16 lanes span one row (256B segments)
    const int r16   = tid >> 4;    // 0..15

    // stage w tile (coalesced: per instr 4 rows x 256B contiguous)
    #pragma unroll
    for (int rb = 0; rb < 4; ++rb) {
        const int r = rb * 16 + r16;
        const int id = sampled[s0 + r];
        const float* src = w + (size_t)id * DIM;
        #pragma unroll
        for (int j = 0; j < 4; ++j) {
            float4 v = *(const float4*)(src + j * 64 + inner * 4);
            ushort4 pk;
            pk.x = f2bf(v.x); pk.y = f2bf(v.y); pk.z = f2bf(v.z); pk.w = f2bf(v.w);
            *(ushort4*)(&lw[r][j * 64 + inner * 4]) = pk;
        }
    }
    if (tid < 64) cs[tid] = comb[sampled[s0 + tid]];

    const int lane = tid & 63;
    const int wv   = tid >> 6;
    const int m    = lane & 15;
    const int quad = lane >> 4;
    const int wy   = wv & 1;
    const int wx   = wv >> 1;

    for (int chunk = 0; chunk < 4; ++chunk) {
        __syncthreads();
        // stage 64 input rows (fp32 -> bf16), same coalesced pattern
        #pragma unroll
        for (int rb = 0; rb < 4; ++rb) {
            const int r = rb * 16 + r16;
            const float* src = inputs + (size_t)(chunk * 64 + r) * DIM;
            #pragma unroll
            for (int j = 0; j < 4; ++j) {
                float4 v = *(const float4*)(src + j * 64 + inner * 4);
                ushort4 pk;
                pk.x = f2bf(v.x); pk.y = f2bf(v.y); pk.z = f2bf(v.z); pk.w = f2bf(v.w);
                *(ushort4*)(&li[r][j * 64 + inner * 4]) = pk;
            }
        }
        __syncthreads();

        f32x4 acc00 = {0,0,0,0}, acc01 = {0,0,0,0}, acc10 = {0,0,0,0}, acc11 = {0,0,0,0};
        const unsigned short* pa0 = &lw[wy * 32 + m][quad * 8];
        const unsigned short* pa1 = &lw[wy * 32 + 16 + m][quad * 8];
        const unsigned short* pb0 = &li[wx * 32 + m][quad * 8];
        const unsigned short* pb1 = &li[wx * 32 + 16 + m][quad * 8];
        #pragma unroll
        for (int kk = 0; kk < 8; ++kk) {
            bf16x8 a0 = *(const bf16x8*)(pa0 + kk * 32);
            bf16x8 a1 = *(const bf16x8*)(pa1 + kk * 32);
            bf16x8 b0 = *(const bf16x8*)(pb0 + kk * 32);
            bf16x8 b1 = *(const bf16x8*)(pb1 + kk * 32);
            acc00 = __builtin_amdgcn_mfma_f32_16x16x32_bf16(a0, b0, acc00, 0, 0, 0);
            acc01 = __builtin_amdgcn_mfma_f32_16x16x32_bf16(a0, b1, acc01, 0, 0, 0);
            acc10 = __builtin_amdgcn_mfma_f32_16x16x32_bf16(a1, b0, acc10, 0, 0, 0);
            acc11 = __builtin_amdgcn_mfma_f32_16x16x32_bf16(a1, b1, acc11, 0, 0, 0);
        }

        // xent(target 0) = max(l,0) + log(1+exp(-|l|))
        float ps0 = 0.0f, ps1 = 0.0f;
        #pragma unroll
        for (int r = 0; r < 4; ++r) {
            {
                float c = cs[wy * 32 + quad * 4 + r];
                float l0 = acc00[r] + c;
                ps0 += fmaxf(l0, 0.0f) + __logf(1.0f + __expf(-fabsf(l0)));
                float l1 = acc01[r] + c;
                ps1 += fmaxf(l1, 0.0f) + __logf(1.0f + __expf(-fabsf(l1)));
            }
            {
                float c = cs[wy * 32 + 16 + quad * 4 + r];
                float l0 = acc10[r] + c;
                ps0 += fmaxf(l0, 0.0f) + __logf(1.0f + __expf(-fabsf(l0)));
                float l1 = acc11[r] + c;
                ps1 += fmaxf(l1, 0.0f) + __logf(1.0f + __expf(-fabsf(l1)));
            }
        }
        ps0 += __shfl_xor(ps0, 16); ps0 += __shfl_xor(ps0, 32);
        ps1 += __shfl_xor(ps1, 16); ps1 += __shfl_xor(ps1, 32);
        if (quad == 0) {
            atomicAdd(&bacc[chunk * 64 + wx * 32 + m], ps0);
            atomicAdd(&bacc[chunk * 64 + wx * 32 + 16 + m], ps1);
        }
    }
    __syncthreads();
    // partial laid out [b][block] so the reduce reads coalesced
    partial[tid * 256 + blockIdx.x] = bacc[tid];
}

// ---------------- final reduce: out[b] = sum_p sampled[b][p] + sum_x true[b][x] ----
__global__ __launch_bounds__(256) void reduce_kernel(const float* __restrict__ partial,
                                                     const float* __restrict__ truep,
                                                     float* __restrict__ out) {
    __shared__ float wsum[4];
    const int b = blockIdx.x;
    const int tid = threadIdx.x;
    float v = partial[b * 256 + tid];
    if (tid < 8) v += truep[b * 8 + tid];
    v += __shfl_xor(v, 1);  v += __shfl_xor(v, 2);  v += __shfl_xor(v, 4);
    v += __shfl_xor(v, 8);  v += __shfl_xor(v, 16); v += __shfl_xor(v, 32);
    if ((tid & 63) == 0) wsum[tid >> 6] = v;
    __syncthreads();
    if (tid == 0) out[b] = wsum[0] + wsum[1] + wsum[2] + wsum[3];
}

extern "C" void kernel_launch(void* const* d_in, const int* in_sizes, int n_in,
                              void* d_out, int out_size, void* d_ws, size_t ws_size,
                              hipStream_t stream) {
    const float* inputs  = (const float*)d_in[0];   // [256,256]
    const float* w       = (const float*)d_in[1];   // [100000,256]
    const float* bias    = (const float*)d_in[2];   // [100000]
    const int*   labels  = (const int*)d_in[3];     // [256,1024]
    const int*   sampled = (const int*)d_in[4];     // [16384]
    float* out = (float*)d_out;                     // [256]

    float* comb    = (float*)d_ws;                              // 400000 B
    float* truep   = (float*)((char*)d_ws + 409600);            // 8 KB
    float* partial = (float*)((char*)d_ws + 417792);            // 256 KB

    comb_kernel<<<(NUM_CLASSES + 255) / 256, 256, 0, stream>>>(bias, comb);
    true_kernel<<<dim3(8, 256), 256, 0, stream>>>(inputs, w, comb, labels, truep);
    sampled_kernel<<<256, 256, 0, stream>>>(w, comb, sampled, inputs, partial);
    reduce_kernel<<<BATCH, 256, 0, stream>>>(partial, truep, out);
}

// Round 5
// 179.048 us; speedup vs baseline: 1.6756x; 1.0588x over previous
//
#include <hip/hip_runtime.h>
#include <hip/hip_bf16.h>

#define NUM_CLASSES 100000
#define DIM 256
#define BATCH 256
#define NUM_TRUE 1024
#define NUM_SAMPLED 16384
// ln(NUM_CLASSES + 1)
#define LOG_RANGE 11.51293546492023f
#define INV_LOG_RANGE (1.0f / LOG_RANGE)

#define SBLOCKS 512   // sampled blocks (32 s-rows each), scheduled FIRST
#define TBLOCKS 2048  // true blocks (128 labels each)

typedef __bf16 bf16x8 __attribute__((ext_vector_type(8)));
typedef float  f32x4  __attribute__((ext_vector_type(4)));

// RNE float -> bf16 bits
static __device__ __forceinline__ unsigned short f2bf(float f) {
    unsigned int u = __float_as_uint(f);
    unsigned int lsb = (u >> 16) & 1u;
    u += 0x7fffu + lsb;
    return (unsigned short)(u >> 16);
}

// -log(expected_count(id)), precise libm (once per class, comb_kernel only)
static __device__ __forceinline__ float neg_log_ec(int id) {
    float idf = (float)id;
    float p = logf((idf + 2.0f) / (idf + 1.0f)) * INV_LOG_RANGE;
    float ec = -expm1f((float)NUM_SAMPLED * log1pf(-p));
    return -logf(ec);
}

static __device__ __forceinline__ float dot4(float4 a, float4 b) {
    return fmaf(a.x, b.x, fmaf(a.y, b.y, fmaf(a.z, b.z, a.w * b.w)));
}

// ---- comb[c] = bias[c] - log(ec(c));  also inputs fp32 -> bf16 into ws ----
__global__ __launch_bounds__(256) void comb_kernel(const float* __restrict__ bias,
                                                   const float* __restrict__ inputs,
                                                   float* __restrict__ comb,
                                                   unsigned short* __restrict__ inbf) {
    int c = blockIdx.x * 256 + threadIdx.x;
    if (c < NUM_CLASSES) comb[c] = bias[c] + neg_log_ec(c);
    if (c < BATCH * DIM) inbf[c] = f2bf(inputs[c]);
}

// ---------------- fused kernel: sampled blocks first, then true ----------------
// LDS budget ~19.6 KB -> 8 blocks/CU by LDS; sampled MFMA work hides under
// true's memory-latency waits (separate MFMA/VALU pipes co-schedule).
__global__ __launch_bounds__(256) void fused_kernel(const float* __restrict__ inputs,
                                                    const float* __restrict__ w,
                                                    const float* __restrict__ comb,
                                                    const int* __restrict__ labels,
                                                    const int* __restrict__ sampled,
                                                    const unsigned short* __restrict__ inbf,
                                                    float* __restrict__ truep,
                                                    float* __restrict__ partial) {
    __shared__ unsigned short lw[32][264];   // w s-tile, bf16 (16.9 KB)
    __shared__ float cs[32];
    __shared__ float bacc[BATCH];
    __shared__ __align__(16) float ins[DIM];
    __shared__ float wsum[4];

    const int tid = threadIdx.x;

    if (blockIdx.x < SBLOCKS) {
        // ================= sampled path: 32 s-rows x 256 batch =================
        const int sblk = blockIdx.x;
        const int s0 = sblk * 32;
        bacc[tid] = 0.0f;

        // stage 32 w rows -> bf16 LDS (per wave-load: 4 rows x 256B = 16 lines)
        const int inner = tid & 15;
        const int r16   = tid >> 4;
        #pragma unroll
        for (int rb = 0; rb < 2; ++rb) {
            const int r = rb * 16 + r16;
            const int id = sampled[s0 + r];
            const float* src = w + (size_t)id * DIM;
            #pragma unroll
            for (int j = 0; j < 4; ++j) {
                float4 v = *(const float4*)(src + j * 64 + inner * 4);
                ushort4 pk;
                pk.x = f2bf(v.x); pk.y = f2bf(v.y); pk.z = f2bf(v.z); pk.w = f2bf(v.w);
                *(ushort4*)(&lw[r][j * 64 + inner * 4]) = pk;
            }
        }
        if (tid < 32) cs[tid] = comb[sampled[s0 + tid]];
        __syncthreads();

        const int lane = tid & 63;
        const int wv   = tid >> 6;
        const int m    = lane & 15;
        const int quad = lane >> 4;
        const int shalf = (wv >> 1) * 16;    // which 16 s-rows
        const int bhalf = (wv & 1) * 128;    // which 128 batch cols

        // A-fragments for this wave's 16 s-rows, all K (8 kk): 32 VGPRs
        bf16x8 af[8];
        #pragma unroll
        for (int kk = 0; kk < 8; ++kk)
            af[kk] = *(const bf16x8*)(&lw[shalf + m][kk * 32 + quad * 8]);

        #pragma unroll
        for (int t = 0; t < 8; ++t) {
            const int brow = bhalf + t * 16 + m;
            const unsigned short* bp = inbf + brow * DIM;
            bf16x8 bf[8];
            #pragma unroll
            for (int kk = 0; kk < 8; ++kk)
                bf[kk] = *(const bf16x8*)(bp + kk * 32 + quad * 8);
            f32x4 acc = {0, 0, 0, 0};
            #pragma unroll
            for (int kk = 0; kk < 8; ++kk)
                acc = __builtin_amdgcn_mfma_f32_16x16x32_bf16(af[kk], bf[kk], acc, 0, 0, 0);
            // C/D: row(s) = quad*4 + r, col(b) = m
            float ps = 0.0f;
            #pragma unroll
            for (int r = 0; r < 4; ++r) {
                float c = cs[shalf + quad * 4 + r];
                float l = acc[r] + c;
                ps += fmaxf(l, 0.0f) + __logf(1.0f + __expf(-fabsf(l)));
            }
            ps += __shfl_xor(ps, 16); ps += __shfl_xor(ps, 32);
            if (quad == 0) atomicAdd(&bacc[bhalf + t * 16 + m], ps);
        }
        __syncthreads();
        partial[tid * SBLOCKS + sblk] = bacc[tid];   // [b][sblk]
    } else {
        // ================= true path: 16 lanes/label, depth-2 pipeline =========
        const int bid  = blockIdx.x - SBLOCKS;
        const int b    = bid >> 3;
        const int chnk = bid & 7;
        ins[tid] = inputs[b * DIM + tid];
        __syncthreads();

        const int lane = tid & 63;
        const int wv   = tid >> 6;
        const int sub  = lane >> 4;
        const int part = lane & 15;
        const float4* ir = (const float4*)ins;
        const float4 in0 = ir[part], in1 = ir[16 + part], in2 = ir[32 + part], in3 = ir[48 + part];

        const int* lab = labels + b * NUM_TRUE + chnk * 128 + wv * 32;

        float4 buf[2][4];
        float  cb[2];
        #pragma unroll
        for (int s = 0; s < 2; ++s) {
            int l = lab[s * 4 + sub];
            const float4* wr = (const float4*)(w + (size_t)l * DIM);
            buf[s][0] = wr[part];      buf[s][1] = wr[16 + part];
            buf[s][2] = wr[32 + part]; buf[s][3] = wr[48 + part];
            cb[s] = comb[l];
        }

        float acc = 0.0f;
        #pragma unroll
        for (int i = 0; i < 8; ++i) {
            const int cur = i & 1;
            float4 w0 = buf[cur][0], w1 = buf[cur][1], w2 = buf[cur][2], w3 = buf[cur][3];
            float cl = cb[cur];
            if (i < 6) {
                int l = lab[(i + 2) * 4 + sub];
                const float4* wr = (const float4*)(w + (size_t)l * DIM);
                buf[cur][0] = wr[part];      buf[cur][1] = wr[16 + part];
                buf[cur][2] = wr[32 + part]; buf[cur][3] = wr[48 + part];
                cb[cur] = comb[l];
            }
            float d = dot4(w0, in0) + dot4(w1, in1) + dot4(w2, in2) + dot4(w3, in3);
            d += __shfl_xor(d, 1); d += __shfl_xor(d, 2);
            d += __shfl_xor(d, 4); d += __shfl_xor(d, 8);
            float logit = d + cl;
            float v = fmaxf(logit, 0.0f) - logit * (1.0f / (float)NUM_TRUE)
                    + __logf(1.0f + __expf(-fabsf(logit)));
            acc += (part == 0) ? v : 0.0f;
        }
        acc += __shfl_xor(acc, 16); acc += __shfl_xor(acc, 32);
        if (lane == 0) wsum[wv] = acc;
        __syncthreads();
        if (tid == 0) truep[b * 8 + chnk] = wsum[0] + wsum[1] + wsum[2] + wsum[3];
    }
}

// ---- final reduce: out[b] = sum_512 sampled partials + sum_8 true partials ----
__global__ __launch_bounds__(256) void reduce_kernel(const float* __restrict__ partial,
                                                     const float* __restrict__ truep,
                                                     float* __restrict__ out) {
    __shared__ float wsum[4];
    const int b = blockIdx.x;
    const int tid = threadIdx.x;
    float v = partial[b * SBLOCKS + tid] + partial[b * SBLOCKS + 256 + tid];
    if (tid < 8) v += truep[b * 8 + tid];
    v += __shfl_xor(v, 1);  v += __shfl_xor(v, 2);  v += __shfl_xor(v, 4);
    v += __shfl_xor(v, 8);  v += __shfl_xor(v, 16); v += __shfl_xor(v, 32);
    if ((tid & 63) == 0) wsum[tid >> 6] = v;
    __syncthreads();
    if (tid == 0) out[b] = wsum[0] + wsum[1] + wsum[2] + wsum[3];
}

extern "C" void kernel_launch(void* const* d_in, const int* in_sizes, int n_in,
                              void* d_out, int out_size, void* d_ws, size_t ws_size,
                              hipStream_t stream) {
    const float* inputs  = (const float*)d_in[0];   // [256,256]
    const float* w       = (const float*)d_in[1];   // [100000,256]
    const float* bias    = (const float*)d_in[2];   // [100000]
    const int*   labels  = (const int*)d_in[3];     // [256,1024]
    const int*   sampled = (const int*)d_in[4];     // [16384]
    float* out = (float*)d_out;                     // [256]

    float*          comb    = (float*)d_ws;                             // 400000 B
    unsigned short* inbf    = (unsigned short*)((char*)d_ws + 409600);  // 128 KB
    float*          truep   = (float*)((char*)d_ws + 540672);           // 8 KB
    float*          partial = (float*)((char*)d_ws + 548864);           // 512 KB

    comb_kernel<<<(NUM_CLASSES + 255) / 256, 256, 0, stream>>>(bias, inputs, comb, inbf);
    fused_kernel<<<SBLOCKS + TBLOCKS, 256, 0, stream>>>(inputs, w, comb, labels,
                                                        sampled, inbf, truep, partial);
    reduce_kernel<<<BATCH, 256, 0, stream>>>(partial, truep, out);
}